// Round 8
// baseline (2053.104 us; speedup 1.0000x reference)
//
#include <hip/hip_runtime.h>
#include <hip/hip_bf16.h>
#include <math.h>

// Problem constants
#define S31   31
#define KC    64
#define KS    7
#define KK    49          // 7*7
#define IMG   128
#define HW    16384       // 128*128
#define LAM   0.1f
#define BNEPS 1e-5f

// conv_z A-tile: plane-major LDS. 4 planes (16B ic-chunks) x 484 pixels,
// HALF the ic range at a time (ks-split, two passes). 30,976 B.
#define PLSTRIDE 3872     // shorts per plane (484 * 8)

// 32x8 tiles for the direct convs (full 128-B cacheline rows)
#define TW    32
#define TH    8
#define DTW   38          // TW + 6
#define DTH   14          // TH + 6
#define DTILE 532         // DTW * DTH

typedef __attribute__((ext_vector_type(8))) short  frag8;   // 8 bf16 (4 VGPRs)
typedef __attribute__((ext_vector_type(4))) float  facc4;   // 4 fp32 acc

// fp32 -> bf16 bits, RNE
static __device__ __forceinline__ short f2bf(float f) {
    union { float f; unsigned u; } x; x.f = f;
    unsigned r = x.u + 0x7fffu + ((x.u >> 16) & 1u);
    return (short)(r >> 16);
}

// ---------------------------------------------------------------------------
// Weight reorder:
//  wz_frag[lyr][khkw][frag f=ks*4+og][lane][j] (bf16) — exact MFMA B-fragment
//    order for 16x16x32: k(=ic) = ks*32 + (lane>>4)*8 + j, n(=oc) = og*16 + (lane&15)
//  wenc_r[lyr][k][oc], wfe_r[k][oc] (fp32)
//  tail: zero pstats (BN partial-sum accumulator)
// ---------------------------------------------------------------------------
__global__ void reorder_weights(const float* __restrict__ Wz,
                                const float* __restrict__ Wenc,
                                const float* __restrict__ Wfe,
                                short* __restrict__ wz_frag,
                                float* __restrict__ wenc_r,
                                float* __restrict__ wfe_r,
                                float* __restrict__ pstats) {
    int tid = blockIdx.x * 256 + threadIdx.x;
    const int NZ = 3 * KK * 4096;         // 602112 frag elements
    const int NE = 3 * KK * KC;           // 9408
    const int NF = KK * KC;               // 3136
    const int NP = 2 * S31 * KC;          // 3968 pstats floats
    if (tid < NZ) {
        int j    = tid & 7;
        int lane = (tid >> 3) & 63;
        int og   = (tid >> 9) & 3;
        int ks   = (tid >> 11) & 1;
        int rem  = tid >> 12;            // lyr*49 + khkw
        int khkw = rem % KK;
        int lyr  = rem / KK;
        int ic = ks * 32 + ((lane >> 4) << 3) + j;
        int oc = (og << 4) + (lane & 15);
        float w = Wz[(((size_t)lyr * KC + oc) * KC + ic) * KK + khkw];
        wz_frag[tid] = f2bf(w);
    } else if (tid < NZ + NE) {
        int t = tid - NZ;
        int oc = t & 63;
        int kk = t >> 6;
        int k  = kk % KK;
        int lyr = kk / KK;
        wenc_r[t] = Wenc[((size_t)lyr * KC + oc) * KK + k];
    } else if (tid < NZ + NE + NF) {
        int t = tid - NZ - NE;
        int oc = t & 63;
        int k  = t >> 6;
        wfe_r[t] = Wfe[oc * KK + k];
    } else if (tid < NZ + NE + NF + NP) {
        pstats[tid - NZ - NE - NF] = 0.f;
    }
}

// ---------------------------------------------------------------------------
// 1 -> 64 channel conv (+optional add) + softshrink.
// 256 threads/block, oc-half on BLOCKIDX (uniform weight addrs -> s_load).
// bf16 copy now goes to SPLIT half-buffers dst_t[half][s][pix][32] so that
// conv_z's two ks-passes each read contiguous 64-B granules (no line sharing)
// and the writes here are full 128-B lines (2 px/line, adjacent threads).
// ---------------------------------------------------------------------------
__global__ __launch_bounds__(256) void conv1to64(
        const float* __restrict__ src,    // [31, HW]
        const float* __restrict__ wr,     // [49*64] layout [k][oc]
        const float* __restrict__ bias,   // [64]
        const float* __restrict__ addsrc, // [31,64,HW] or nullptr
        float* __restrict__ dst,          // [31,64,HW]
        short* __restrict__ dst_t)        // [2][31][HW][32] bf16 or nullptr
{
    int s    = blockIdx.y;
    int half = blockIdx.x & 1;            // 0/1 -> oc 0..31 / 32..63 (UNIFORM)
    int tile = blockIdx.x >> 1;           // 4 tiles in w (32 wide), 16 in h (8 tall)
    int t    = threadIdx.x;
    int tx = t & 31, ty = t >> 5;
    int w0 = (tile & 3) << 5, h0 = (tile >> 2) << 3;

    __shared__ float t_s[DTILE];
    const float* sp = src + (size_t)s * HW;
    for (int i = threadIdx.x; i < DTILE; i += 256) {
        int r = i / DTW, c = i - r * DTW;
        int hh = h0 - 3 + r, ww = w0 - 3 + c;
        t_s[i] = (hh >= 0 && hh < IMG && ww >= 0 && ww < IMG) ? sp[hh * IMG + ww] : 0.f;
    }
    __syncthreads();

    int pix = (h0 + ty) * IMG + (w0 + tx);
    size_t base = ((size_t)s * KC + half * 32) * HW + pix;

    // 32-deep prefetch of addsrc (issued before the compute loop, kept live)
    float addv[32];
    if (addsrc) {
#pragma unroll
        for (int i = 0; i < 32; i++) addv[i] = addsrc[base + (size_t)i * HW];
    } else {
#pragma unroll
        for (int i = 0; i < 32; i++) addv[i] = 0.f;
    }
    __builtin_amdgcn_sched_barrier(0);   // keep the loads issued up here

    float acc[32];
#pragma unroll
    for (int i = 0; i < 32; i++) acc[i] = 0.f;

    const float* wrh = wr + half * 32;   // uniform -> scalar loads below
#pragma unroll 1
    for (int kh = 0; kh < KS; kh++) {
#pragma unroll
        for (int kw = 0; kw < KS; kw++) {
            float v = t_s[(ty + kh) * DTW + tx + kw];
            const float* wk = wrh + (kh * KS + kw) * KC;
#pragma unroll
            for (int i = 0; i < 32; i++) acc[i] += v * wk[i];
        }
    }

    short* tb = dst_t ? (dst_t + (((size_t)half * S31 + s) * HW + pix) * 32) : nullptr;
#pragma unroll
    for (int g = 0; g < 4; g++) {
        frag8 vv;
#pragma unroll
        for (int j = 0; j < 8; j++) {
            int i = g * 8 + j;
            float v = acc[i] + bias[half * 32 + i];   // same assoc order as R7
            v += addv[i];                             // (+0.0f when no addsrc)
            v = (v > LAM) ? (v - LAM) : ((v < -LAM) ? (v + LAM) : 0.f);
            dst[base + (size_t)i * HW] = v;
            vv[j] = f2bf(v);
        }
        if (tb) *(frag8*)(tb + g * 8) = vv;
    }
}

// ---------------------------------------------------------------------------
// 64 -> 1 channel conv. If xsub != null, out = xsub - (conv+b); else conv+b.
// 32x8 tile; ic staged 4 planes/round, double-buffered LDS with register
// prefetch. Accumulation order (ic asc, kh, kw) identical -> bit-exact.
// ---------------------------------------------------------------------------
#define ICB   4
#define CHUNK (ICB * DTILE)   // 2128

__global__ __launch_bounds__(256) void conv64to1(
        const float* __restrict__ src,   // [31,64,HW]
        const float* __restrict__ w,     // [64*49] layout [ic][k]
        const float* __restrict__ bias,  // [1]
        const float* __restrict__ xsub,  // [31,HW] or nullptr
        float* __restrict__ dst)         // [31,HW]
{
    int s    = blockIdx.y;
    int tile = blockIdx.x;
    int tx = threadIdx.x & 31, ty = threadIdx.x >> 5;
    int w0 = (tile & 3) << 5, h0 = (tile >> 2) << 3;

    __shared__ float t_s[2][CHUNK];      // 17 KB

    // per-thread load slots: identical pattern every chunk, precompute once
    int  goff[9];
    bool okf[9];
#pragma unroll
    for (int r = 0; r < 9; r++) {
        int j = threadIdx.x + r * 256;
        if (j < CHUNK) {
            int plane = j / DTILE, p = j - plane * DTILE;
            int rr = p / DTW, cc = p - rr * DTW;
            int hh = h0 - 3 + rr, ww = w0 - 3 + cc;
            bool inb = (hh >= 0 && hh < IMG && ww >= 0 && ww < IMG);
            goff[r] = plane * HW + (inb ? (hh * IMG + ww) : 0);
            okf[r]  = inb;
        }
    }

    const float* sbase = src + (size_t)s * KC * HW;

    // stage chunk 0
    float ldv[9];
#pragma unroll
    for (int r = 0; r < 9; r++)
        if (threadIdx.x + r * 256 < CHUNK)
            ldv[r] = okf[r] ? sbase[goff[r]] : 0.f;
#pragma unroll
    for (int r = 0; r < 9; r++)
        if (threadIdx.x + r * 256 < CHUNK)
            t_s[0][threadIdx.x + r * 256] = ldv[r];

    float acc = 0.f;
    __syncthreads();

#pragma unroll 1
    for (int blk = 0; blk < 16; blk++) {
        int cur = blk & 1;
        // prefetch next chunk into regs (overlaps the compute below)
        if (blk < 15) {
            const float* nb = sbase + (size_t)(blk + 1) * ICB * HW;
#pragma unroll
            for (int r = 0; r < 9; r++)
                if (threadIdx.x + r * 256 < CHUNK)
                    ldv[r] = okf[r] ? nb[goff[r]] : 0.f;
        }
        __builtin_amdgcn_sched_barrier(0);
        // compute 4 planes of this chunk
#pragma unroll
        for (int pl = 0; pl < ICB; pl++) {
            int ic = blk * ICB + pl;
            const float* wk = w + ic * KK;
            const float* ts = &t_s[cur][pl * DTILE];
#pragma unroll 1
            for (int kh = 0; kh < KS; kh++) {
#pragma unroll
                for (int kw = 0; kw < KS; kw++)
                    acc += ts[(ty + kh) * DTW + tx + kw] * wk[kh * KS + kw];
            }
        }
        __syncthreads();
        if (blk < 15) {
#pragma unroll
            for (int r = 0; r < 9; r++)
                if (threadIdx.x + r * 256 < CHUNK)
                    t_s[cur ^ 1][threadIdx.x + r * 256] = ldv[r];
            __syncthreads();
        }
    }

    float v = acc + bias[0];
    int pix = (h0 + ty) * IMG + (w0 + tx);
    if (xsub) v = xsub[(size_t)s * HW + pix] - v;
    dst[(size_t)s * HW + pix] = v;
}

// ---------------------------------------------------------------------------
// conv_z as bf16 MFMA shift-GEMM.
// R8: 512 threads (8 waves); each wave owns 2 px-rows -> acc[2][4] = 32 AGPRs
//   (was 64). __launch_bounds__(512,4) = 128 unified regs/wave leaves ~44
//   free -> explicit 1-deep next-tap B prefetch (R7 had ZERO headroom:
//   64 acc + 64 arch = exactly 128 -> B-load latency fully exposed, util 44%).
// srcT is now SPLIT per pass: [pass][s][pix][32ic] -> each pass reads
//   contiguous 64-B granules; kills R7's 90 MB double-fetch (line sharing).
// ks-SPLIT kept: LDS 30,976 B; 2 blocks/CU x 8 waves = 16 waves/CU.
// First-tap B loads issue BEFORE staging (independent) to overlap.
// Accumulation order per (px,oc) identical to R7 -> bit-exact.
// ---------------------------------------------------------------------------
__global__ __launch_bounds__(512, 4) void conv_z_mfma(
        const short* __restrict__ srcT,  // [2][31][HW][32] bf16 (tmp_t halves)
        const short* __restrict__ wfrag, // per-layer B-frag buffer (bf16 bits)
        const float* __restrict__ bias,  // [64]
        float* __restrict__ dst,         // [31,64,HW] (zpre)
        float* __restrict__ pstats)      // [31*64][2] partial sums (pre-zeroed)
{
    __shared__ __align__(16) short a_s[4 * PLSTRIDE]; // 30,976 B

    int s    = blockIdx.y;
    int tile = blockIdx.x;
    int h0 = (tile >> 3) << 4, w0 = (tile & 7) << 4;
    int tid  = threadIdx.x;
    int wave = tid >> 6, lane = tid & 63;
    int q = lane >> 4, m = lane & 15;

    facc4 acc[2][4];
#pragma unroll
    for (int i = 0; i < 2; i++)
#pragma unroll
        for (int j = 0; j < 4; j++)
            acc[i][j] = (facc4){0.f, 0.f, 0.f, 0.f};

#pragma unroll 1
    for (int pass = 0; pass < 2; ++pass) {
        if (pass) __syncthreads();       // all pass-0 reads done before overwrite

        // B base for this pass; issue first-tap loads EARLY (overlap staging)
        const frag8* brow = (const frag8*)wfrag + (pass * 4) * 64 + lane;
        frag8 c0 = brow[0], c1 = brow[64], c2 = brow[128], c3 = brow[192];

        // ---- stage ic half [pass*32, pass*32+32) -> planes 0..3 (b128 only)
        const short* tsrc = srcT + ((size_t)pass * S31 + s) * HW * 32;
        {
            int p = tid;
            if (p < 484) {
                int r = p / 22, c = p - r * 22;
                int hh = h0 - 3 + r, ww = w0 - 3 + c;
                bool ok = (hh >= 0 && hh < IMG && ww >= 0 && ww < IMG);
                const short* px = tsrc + (size_t)(ok ? (hh * IMG + ww) : 0) * 32;
                short* dp = a_s + p * 8;
#pragma unroll
                for (int c4 = 0; c4 < 4; c4++) {
                    frag8 v;
                    if (ok) v = *(const frag8*)(px + (c4 << 3));
                    else    v = (frag8)(short)0;
                    *(frag8*)(dp + c4 * PLSTRIDE) = v;
                }
            }
        }
        __syncthreads();

        // per-lane A base: plane q, pixel row (wave*2), col m
        const short* arow = a_s + q * PLSTRIDE + (wave * 2 * 22 + m) * 8;

#pragma unroll 1
        for (int kh = 0; kh < 7; ++kh) {
#pragma unroll
            for (int kw = 0; kw < 7; ++kw) {
                // prefetch next tap's B frags (kw+1, or next kh row's kw=0;
                // last tap reads 1-tap slack appended after wz_frag)
                const frag8* bn = brow + (kw == 6 ? 7 : (kw + 1)) * 512;
                frag8 n0 = bn[0], n1 = bn[64], n2 = bn[128], n3 = bn[192];
                frag8 a0 = *(const frag8*)(arow + (0 * 22 + kw) * 8);
                frag8 a1 = *(const frag8*)(arow + (1 * 22 + kw) * 8);
                acc[0][0] = __builtin_amdgcn_mfma_f32_16x16x32_bf16(a0, c0, acc[0][0], 0, 0, 0);
                acc[0][1] = __builtin_amdgcn_mfma_f32_16x16x32_bf16(a0, c1, acc[0][1], 0, 0, 0);
                acc[0][2] = __builtin_amdgcn_mfma_f32_16x16x32_bf16(a0, c2, acc[0][2], 0, 0, 0);
                acc[0][3] = __builtin_amdgcn_mfma_f32_16x16x32_bf16(a0, c3, acc[0][3], 0, 0, 0);
                acc[1][0] = __builtin_amdgcn_mfma_f32_16x16x32_bf16(a1, c0, acc[1][0], 0, 0, 0);
                acc[1][1] = __builtin_amdgcn_mfma_f32_16x16x32_bf16(a1, c1, acc[1][1], 0, 0, 0);
                acc[1][2] = __builtin_amdgcn_mfma_f32_16x16x32_bf16(a1, c2, acc[1][2], 0, 0, 0);
                acc[1][3] = __builtin_amdgcn_mfma_f32_16x16x32_bf16(a1, c3, acc[1][3], 0, 0, 0);
                c0 = n0; c1 = n1; c2 = n2; c3 = n3;   // rotate (renamed, unrolled)
            }
            arow += 22 * 8;     // next kh row of the A tile
            brow += 7 * 512;    // next row of 7 taps in wz_frag
        }
    }

    // ---- epilogue: D layout col(oc-part)=lane&15, row(px col)=q*4+reg
    //      + fused BN partial sums (per oc: reduce over q-lanes, atomicAdd)
    int prow = h0 + wave * 2;
#pragma unroll
    for (int og = 0; og < 4; og++) {
        int oc = og * 16 + m;
        float bb = bias[oc];
        float s1 = 0.f, s2 = 0.f;
#pragma unroll
        for (int pg = 0; pg < 2; pg++) {
            float* dp = dst + ((size_t)s * KC + oc) * HW
                            + (size_t)(prow + pg) * IMG + w0 + q * 4;
            float4 v;
            v.x = acc[pg][og][0] + bb;
            v.y = acc[pg][og][1] + bb;
            v.z = acc[pg][og][2] + bb;
            v.w = acc[pg][og][3] + bb;
            s1 += v.x + v.y + v.z + v.w;
            s2 += v.x * v.x + v.y * v.y + v.z * v.z + v.w * v.w;
            *(float4*)dp = v;
        }
        // reduce over the 4 q-lanes sharing this oc (lane bits 4,5)
        s1 += __shfl_xor(s1, 16, 64); s2 += __shfl_xor(s2, 16, 64);
        s1 += __shfl_xor(s1, 32, 64); s2 += __shfl_xor(s2, 32, 64);
        if (q == 0) {
            atomicAdd(&pstats[(s * KC + oc) * 2],     s1);
            atomicAdd(&pstats[(s * KC + oc) * 2 + 1], s2);
        }
    }
}

// ---------------------------------------------------------------------------
// Finalize BN stats from fused partial sums; re-zero pstats for next iter.
// ---------------------------------------------------------------------------
__global__ __launch_bounds__(64) void bn_finalize(
        float* __restrict__ pstats,   // [31*64][2] partial sums
        float* __restrict__ stats)    // [31*64][2] -> (mu, rsqrt(var+eps))
{
    int i = blockIdx.x * 64 + threadIdx.x;
    if (i < S31 * KC) {
        float s1 = pstats[i * 2], s2 = pstats[i * 2 + 1];
        pstats[i * 2] = 0.f;
        pstats[i * 2 + 1] = 0.f;
        float mu  = s1 * (1.f / HW);
        float var = s2 * (1.f / HW) - mu * mu;
        if (var < 0.f) var = 0.f;
        stats[i * 2]     = mu;
        stats[i * 2 + 1] = rsqrtf(var + BNEPS);
    }
}

// ---------------------------------------------------------------------------
// Directional gated band scan: each thread owns one (c,h,w), walks 31 bands.
// ---------------------------------------------------------------------------
__global__ __launch_bounds__(256) void band_scan(
        const float* __restrict__ tmp,   // [31,64,HW]
        const float* __restrict__ zpre,  // [31,64,HW]
        const float* __restrict__ stats, // [31*64][2]
        const float* __restrict__ gamma, // [64]
        const float* __restrict__ beta,  // [64]
        float* __restrict__ csc,         // [31,64,HW]
        int fwd)
{
    int idx = blockIdx.x * 256 + threadIdx.x;  // 0 .. 64*HW-1
    int c = idx >> 14;
    float g = gamma[c], be = beta[c];
    float prev = 0.f;
    for (int step = 0; step < S31; step++) {
        int s = fwd ? step : (S31 - 1 - step);
        size_t off = (size_t)s * KC * HW + idx;
        float t  = tmp[off];
        float zp = zpre[off];
        float mu = stats[(s * KC + c) * 2];
        float rs = stats[(s * KC + c) * 2 + 1];
        float zn = (zp - mu) * rs * g + be;
        float z  = 1.f / (1.f + expf(-zn));
        float cur = (step == 0) ? t : (z * prev + (1.f - z) * t);
        csc[off] = cur;
        prev = cur;
    }
}

// ---------------------------------------------------------------------------
extern "C" void kernel_launch(void* const* d_in, const int* in_sizes, int n_in,
                              void* d_out, int out_size, void* d_ws, size_t ws_size,
                              hipStream_t stream) {
    const float* x      = (const float*)d_in[0];   // [1,31,128,128]
    const float* W_fe   = (const float*)d_in[1];
    const float* b_fe   = (const float*)d_in[2];
    const float* W_enc  = (const float*)d_in[3];
    const float* b_enc  = (const float*)d_in[4];
    const float* W_dec  = (const float*)d_in[5];
    const float* b_dec  = (const float*)d_in[6];
    const float* W_last = (const float*)d_in[7];
    const float* b_last = (const float*)d_in[8];
    const float* W_z    = (const float*)d_in[9];
    const float* b_z    = (const float*)d_in[10];
    const float* bn_g   = (const float*)d_in[11];
    const float* bn_b   = (const float*)d_in[12];

    float* out     = (float*)d_out;
    float* csc     = out;                               // [31,1,64,128,128]
    float* outputs = out + (size_t)S31 * KC * HW;       // [1,31,128,128]

    char* ws = (char*)d_ws;
    float* tmp     = (float*)ws; ws += (size_t)S31 * KC * HW * 4;
    float* zpre    = (float*)ws; ws += (size_t)S31 * KC * HW * 4;
    float* res     = (float*)ws; ws += (size_t)S31 * HW * 4;
    float* stats   = (float*)ws; ws += (size_t)S31 * KC * 2 * 4;
    float* pstats  = (float*)ws; ws += (size_t)S31 * KC * 2 * 4;
    short* wz_frag = (short*)ws; ws += ((size_t)3 * KK * 4096 + 4096) * 2; // +1 tap slack (prefetch)
    float* wenc_r  = (float*)ws; ws += (size_t)3 * KK * KC * 4;
    float* wfe_r   = (float*)ws; ws += (size_t)KK * KC * 4;
    short* tmp_t   = (short*)ws; ws += (size_t)2 * S31 * HW * 32 * 2;  // bf16 [pass][s][pix][32]

    // 1) weight reorder / frag-swizzle (+ zero pstats)
    {
        int total = 3 * KK * 4096 + 3 * KK * KC + KK * KC + 2 * S31 * KC;
        reorder_weights<<<(total + 255) / 256, 256, 0, stream>>>(
            W_z, W_enc, W_fe, wz_frag, wenc_r, wfe_r, pstats);
    }

    dim3 gconv(64, S31);     // conv64to1 / conv_z grids
    dim3 gconv2(128, S31);   // conv1to64: 64 tiles x 2 oc-halves

    // 2) csc = softshrink(conv_fe(x))
    conv1to64<<<gconv2, 256, 0, stream>>>(x, wfe_r, b_fe, nullptr, csc, nullptr);

    for (int it = 0; it < 3; it++) {
        int lyr = it;
        // res = x - (conv_dec(csc) + b_dec)
        conv64to1<<<gconv, 256, 0, stream>>>(
            csc, W_dec + (size_t)lyr * KC * KK, b_dec + lyr, x, res);
        // tmp = softshrink(csc + conv_enc(res) + b_enc)  (+ bf16 split copies)
        conv1to64<<<gconv2, 256, 0, stream>>>(
            res, wenc_r + (size_t)lyr * KK * KC, b_enc + (size_t)lyr * KC, csc,
            tmp, tmp_t);
        // zpre = conv_z(tmp) + b_z   (bf16 MFMA shift-GEMM, 8 waves, B prefetch,
        //                             split srcT, fused BN)
        conv_z_mfma<<<gconv, 512, 0, stream>>>(
            tmp_t, wz_frag + (size_t)lyr * KK * 4096, b_z + (size_t)lyr * KC,
            zpre, pstats);
        // BN finalize (also re-zeroes pstats for the next iteration)
        bn_finalize<<<S31, 64, 0, stream>>>(pstats, stats);
        // gated directional scan -> csc
        band_scan<<<(KC * HW) / 256, 256, 0, stream>>>(
            tmp, zpre, stats, bn_g + (size_t)lyr * KC, bn_b + (size_t)lyr * KC,
            csc, (it % 2 == 0) ? 1 : 0);
    }

    // 3) outputs = conv_last(csc) + b_last
    conv64to1<<<gconv, 256, 0, stream>>>(csc, W_last, b_last, nullptr, outputs);
}

// Round 9
// 1749.019 us; speedup vs baseline: 1.1739x; 1.1739x over previous
//
#include <hip/hip_runtime.h>
#include <hip/hip_bf16.h>
#include <math.h>

// Problem constants
#define S31   31
#define KC    64
#define KS    7
#define KK    49          // 7*7
#define IMG   128
#define HW    16384       // 128*128
#define LAM   0.1f
#define BNEPS 1e-5f

// conv_z A-tile: plane-major LDS. 4 planes (16B ic-chunks) x 484 pixels,
// HALF the ic range at a time (ks-split, two passes). 30,976 B.
#define PLSTRIDE 3872     // shorts per plane (484 * 8)

// 32x8 tiles for the direct convs (full 128-B cacheline rows)
#define TW    32
#define TH    8
#define DTW   38          // TW + 6
#define DTH   14          // TH + 6
#define DTILE 532         // DTW * DTH

typedef __attribute__((ext_vector_type(8))) short  frag8;   // 8 bf16 (4 VGPRs)
typedef __attribute__((ext_vector_type(4))) float  facc4;   // 4 fp32 acc

// fp32 -> bf16 bits, RNE
static __device__ __forceinline__ short f2bf(float f) {
    union { float f; unsigned u; } x; x.f = f;
    unsigned r = x.u + 0x7fffu + ((x.u >> 16) & 1u);
    return (short)(r >> 16);
}

// ---------------------------------------------------------------------------
// Weight reorder:
//  wz_frag[lyr][khkw][frag f=ks*4+og][lane][j] (bf16) — exact MFMA B-fragment
//    order for 16x16x32: k(=ic) = ks*32 + (lane>>4)*8 + j, n(=oc) = og*16 + (lane&15)
//  wenc_r[lyr][k][oc], wfe_r[k][oc] (fp32)
//  tail: zero pstats (BN partial-sum accumulator)
// ---------------------------------------------------------------------------
__global__ void reorder_weights(const float* __restrict__ Wz,
                                const float* __restrict__ Wenc,
                                const float* __restrict__ Wfe,
                                short* __restrict__ wz_frag,
                                float* __restrict__ wenc_r,
                                float* __restrict__ wfe_r,
                                float* __restrict__ pstats) {
    int tid = blockIdx.x * 256 + threadIdx.x;
    const int NZ = 3 * KK * 4096;         // 602112 frag elements
    const int NE = 3 * KK * KC;           // 9408
    const int NF = KK * KC;               // 3136
    const int NP = 2 * S31 * KC;          // 3968 pstats floats
    if (tid < NZ) {
        int j    = tid & 7;
        int lane = (tid >> 3) & 63;
        int og   = (tid >> 9) & 3;
        int ks   = (tid >> 11) & 1;
        int rem  = tid >> 12;            // lyr*49 + khkw
        int khkw = rem % KK;
        int lyr  = rem / KK;
        int ic = ks * 32 + ((lane >> 4) << 3) + j;
        int oc = (og << 4) + (lane & 15);
        float w = Wz[(((size_t)lyr * KC + oc) * KC + ic) * KK + khkw];
        wz_frag[tid] = f2bf(w);
    } else if (tid < NZ + NE) {
        int t = tid - NZ;
        int oc = t & 63;
        int kk = t >> 6;
        int k  = kk % KK;
        int lyr = kk / KK;
        wenc_r[t] = Wenc[((size_t)lyr * KC + oc) * KK + k];
    } else if (tid < NZ + NE + NF) {
        int t = tid - NZ - NE;
        int oc = t & 63;
        int k  = t >> 6;
        wfe_r[t] = Wfe[oc * KK + k];
    } else if (tid < NZ + NE + NF + NP) {
        pstats[tid - NZ - NE - NF] = 0.f;
    }
}

// ---------------------------------------------------------------------------
// 1 -> 64 channel conv (+optional add) + softshrink.
// 256 threads/block, oc-half on BLOCKIDX (uniform weight addrs -> s_load).
// bf16 copy goes to SPLIT half-buffers dst_t[half][s][pix][32] so that
// conv_z's two ks-passes each read contiguous 64-B granules.
// ---------------------------------------------------------------------------
__global__ __launch_bounds__(256) void conv1to64(
        const float* __restrict__ src,    // [31, HW]
        const float* __restrict__ wr,     // [49*64] layout [k][oc]
        const float* __restrict__ bias,   // [64]
        const float* __restrict__ addsrc, // [31,64,HW] or nullptr
        float* __restrict__ dst,          // [31,64,HW]
        short* __restrict__ dst_t)        // [2][31][HW][32] bf16 or nullptr
{
    int s    = blockIdx.y;
    int half = blockIdx.x & 1;            // 0/1 -> oc 0..31 / 32..63 (UNIFORM)
    int tile = blockIdx.x >> 1;           // 4 tiles in w (32 wide), 16 in h (8 tall)
    int t    = threadIdx.x;
    int tx = t & 31, ty = t >> 5;
    int w0 = (tile & 3) << 5, h0 = (tile >> 2) << 3;

    __shared__ float t_s[DTILE];
    const float* sp = src + (size_t)s * HW;
    for (int i = threadIdx.x; i < DTILE; i += 256) {
        int r = i / DTW, c = i - r * DTW;
        int hh = h0 - 3 + r, ww = w0 - 3 + c;
        t_s[i] = (hh >= 0 && hh < IMG && ww >= 0 && ww < IMG) ? sp[hh * IMG + ww] : 0.f;
    }
    __syncthreads();

    int pix = (h0 + ty) * IMG + (w0 + tx);
    size_t base = ((size_t)s * KC + half * 32) * HW + pix;

    // 32-deep prefetch of addsrc (issued before the compute loop, kept live)
    float addv[32];
    if (addsrc) {
#pragma unroll
        for (int i = 0; i < 32; i++) addv[i] = addsrc[base + (size_t)i * HW];
    } else {
#pragma unroll
        for (int i = 0; i < 32; i++) addv[i] = 0.f;
    }
    __builtin_amdgcn_sched_barrier(0);   // keep the loads issued up here

    float acc[32];
#pragma unroll
    for (int i = 0; i < 32; i++) acc[i] = 0.f;

    const float* wrh = wr + half * 32;   // uniform -> scalar loads below
#pragma unroll 1
    for (int kh = 0; kh < KS; kh++) {
#pragma unroll
        for (int kw = 0; kw < KS; kw++) {
            float v = t_s[(ty + kh) * DTW + tx + kw];
            const float* wk = wrh + (kh * KS + kw) * KC;
#pragma unroll
            for (int i = 0; i < 32; i++) acc[i] += v * wk[i];
        }
    }

    short* tb = dst_t ? (dst_t + (((size_t)half * S31 + s) * HW + pix) * 32) : nullptr;
#pragma unroll
    for (int g = 0; g < 4; g++) {
        frag8 vv;
#pragma unroll
        for (int j = 0; j < 8; j++) {
            int i = g * 8 + j;
            float v = acc[i] + bias[half * 32 + i];   // same assoc order as R7
            v += addv[i];                             // (+0.0f when no addsrc)
            v = (v > LAM) ? (v - LAM) : ((v < -LAM) ? (v + LAM) : 0.f);
            dst[base + (size_t)i * HW] = v;
            vv[j] = f2bf(v);
        }
        if (tb) *(frag8*)(tb + g * 8) = vv;
    }
}

// ---------------------------------------------------------------------------
// 64 -> 1 channel conv. If xsub != null, out = xsub - (conv+b); else conv+b.
// 32x8 tile; ic staged 4 planes/round, double-buffered LDS with register
// prefetch. Accumulation order (ic asc, kh, kw) identical -> bit-exact.
// ---------------------------------------------------------------------------
#define ICB   4
#define CHUNK (ICB * DTILE)   // 2128

__global__ __launch_bounds__(256) void conv64to1(
        const float* __restrict__ src,   // [31,64,HW]
        const float* __restrict__ w,     // [64*49] layout [ic][k]
        const float* __restrict__ bias,  // [1]
        const float* __restrict__ xsub,  // [31,HW] or nullptr
        float* __restrict__ dst)         // [31,HW]
{
    int s    = blockIdx.y;
    int tile = blockIdx.x;
    int tx = threadIdx.x & 31, ty = threadIdx.x >> 5;
    int w0 = (tile & 3) << 5, h0 = (tile >> 2) << 3;

    __shared__ float t_s[2][CHUNK];      // 17 KB

    // per-thread load slots: identical pattern every chunk, precompute once
    int  goff[9];
    bool okf[9];
#pragma unroll
    for (int r = 0; r < 9; r++) {
        int j = threadIdx.x + r * 256;
        if (j < CHUNK) {
            int plane = j / DTILE, p = j - plane * DTILE;
            int rr = p / DTW, cc = p - rr * DTW;
            int hh = h0 - 3 + rr, ww = w0 - 3 + cc;
            bool inb = (hh >= 0 && hh < IMG && ww >= 0 && ww < IMG);
            goff[r] = plane * HW + (inb ? (hh * IMG + ww) : 0);
            okf[r]  = inb;
        }
    }

    const float* sbase = src + (size_t)s * KC * HW;

    // stage chunk 0
    float ldv[9];
#pragma unroll
    for (int r = 0; r < 9; r++)
        if (threadIdx.x + r * 256 < CHUNK)
            ldv[r] = okf[r] ? sbase[goff[r]] : 0.f;
#pragma unroll
    for (int r = 0; r < 9; r++)
        if (threadIdx.x + r * 256 < CHUNK)
            t_s[0][threadIdx.x + r * 256] = ldv[r];

    float acc = 0.f;
    __syncthreads();

#pragma unroll 1
    for (int blk = 0; blk < 16; blk++) {
        int cur = blk & 1;
        // prefetch next chunk into regs (overlaps the compute below)
        if (blk < 15) {
            const float* nb = sbase + (size_t)(blk + 1) * ICB * HW;
#pragma unroll
            for (int r = 0; r < 9; r++)
                if (threadIdx.x + r * 256 < CHUNK)
                    ldv[r] = okf[r] ? nb[goff[r]] : 0.f;
        }
        __builtin_amdgcn_sched_barrier(0);
        // compute 4 planes of this chunk
#pragma unroll
        for (int pl = 0; pl < ICB; pl++) {
            int ic = blk * ICB + pl;
            const float* wk = w + ic * KK;
            const float* ts = &t_s[cur][pl * DTILE];
#pragma unroll 1
            for (int kh = 0; kh < KS; kh++) {
#pragma unroll
                for (int kw = 0; kw < KS; kw++)
                    acc += ts[(ty + kh) * DTW + tx + kw] * wk[kh * KS + kw];
            }
        }
        __syncthreads();
        if (blk < 15) {
#pragma unroll
            for (int r = 0; r < 9; r++)
                if (threadIdx.x + r * 256 < CHUNK)
                    t_s[cur ^ 1][threadIdx.x + r * 256] = ldv[r];
            __syncthreads();
        }
    }

    float v = acc + bias[0];
    int pix = (h0 + ty) * IMG + (w0 + tx);
    if (xsub) v = xsub[(size_t)s * HW + pix] - v;
    dst[(size_t)s * HW + pix] = v;
}

// ---------------------------------------------------------------------------
// conv_z as bf16 MFMA shift-GEMM.
// R9: back to R7's 4-wave / acc[4][4] / 16-MFMA-per-tap structure (R8's
//   8-wave split halved per-wave MFMA per tap while keeping B-load work ->
//   B-bytes/MFMA doubled, util 44->28%). New: software PIPELINE.
//   __launch_bounds__(256,3) -> 170 regs/wave (R7's (256,4) was exactly 128:
//   zero headroom, loads fully exposed). Budget: 64 acc AGPR + cur A/B 32 +
//   NEXT-TAP A/B prefetch 32 + addr ~ 150. Each kw body issues next tap's
//   4 ds_read_b128 + 4 B global loads, then 16 MFMAs on current regs.
// srcT SPLIT per pass [pass][s][pix][32]: contiguous 64-B reads (R8's fix,
//   FETCH 90->52 MB). ks-split kept (LDS 30,976 B, 3 blocks/CU = 12 waves).
// MFMA order identical to R7/R8 -> bit-exact.
// ---------------------------------------------------------------------------
__global__ __launch_bounds__(256, 3) void conv_z_mfma(
        const short* __restrict__ srcT,  // [2][31][HW][32] bf16 (tmp_t halves)
        const short* __restrict__ wfrag, // per-layer B-frag buffer (bf16 bits)
        const float* __restrict__ bias,  // [64]
        float* __restrict__ dst,         // [31,64,HW] (zpre)
        float* __restrict__ pstats)      // [31*64][2] partial sums (pre-zeroed)
{
    __shared__ __align__(16) short a_s[4 * PLSTRIDE]; // 30,976 B

    int s    = blockIdx.y;
    int tile = blockIdx.x;
    int h0 = (tile >> 3) << 4, w0 = (tile & 7) << 4;
    int tid  = threadIdx.x;
    int wave = tid >> 6, lane = tid & 63;
    int q = lane >> 4, m = lane & 15;

    facc4 acc[4][4];
#pragma unroll
    for (int i = 0; i < 4; i++)
#pragma unroll
        for (int j = 0; j < 4; j++)
            acc[i][j] = (facc4){0.f, 0.f, 0.f, 0.f};

#pragma unroll 1
    for (int pass = 0; pass < 2; ++pass) {
        if (pass) __syncthreads();       // all pass-0 reads done before overwrite

        // ---- stage ic half [pass*32, pass*32+32) -> planes 0..3 (b128 only)
        const short* tsrc = srcT + ((size_t)pass * S31 + s) * HW * 32;
#pragma unroll
        for (int rep = 0; rep < 2; rep++) {
            int p = tid + rep * 256;
            if (p < 484) {
                int r = p / 22, c = p - r * 22;
                int hh = h0 - 3 + r, ww = w0 - 3 + c;
                bool ok = (hh >= 0 && hh < IMG && ww >= 0 && ww < IMG);
                const short* px = tsrc + (size_t)(ok ? (hh * IMG + ww) : 0) * 32;
                short* dp = a_s + p * 8;
#pragma unroll
                for (int c4 = 0; c4 < 4; c4++) {
                    frag8 v;
                    if (ok) v = *(const frag8*)(px + (c4 << 3));
                    else    v = (frag8)(short)0;
                    *(frag8*)(dp + c4 * PLSTRIDE) = v;
                }
            }
        }
        __syncthreads();

        // per-lane bases
        const short* arow = a_s + q * PLSTRIDE + (wave * 4 * 22 + m) * 8;
        const frag8* brow = (const frag8*)wfrag + (pass * 4) * 64 + lane;

        // ---- preload tap (kh=0, kw=0)
        frag8 ca0 = *(const frag8*)(arow + (0 * 22) * 8);
        frag8 ca1 = *(const frag8*)(arow + (1 * 22) * 8);
        frag8 ca2 = *(const frag8*)(arow + (2 * 22) * 8);
        frag8 ca3 = *(const frag8*)(arow + (3 * 22) * 8);
        frag8 cb0 = brow[0], cb1 = brow[64], cb2 = brow[128], cb3 = brow[192];

#pragma unroll 1
        for (int kh = 0; kh < 7; ++kh) {
            // next kh row base (at kh==6 re-point to current row: prefetch
            // results are discarded after the last tap)
            const short* arow_n = (kh < 6) ? (arow + 22 * 8) : arow;
#pragma unroll
            for (int kw = 0; kw < 7; ++kw) {
                // ---- issue next tap's loads (A: LDS, B: global/L1)
                const short* an = (kw < 6) ? arow : arow_n;
                const int koff = (kw < 6) ? (kw + 1) : 0;
                const frag8* bn = brow + (kw + 1) * 512;   // kw==6 -> next row
                frag8 na0 = *(const frag8*)(an + (0 * 22 + koff) * 8);
                frag8 na1 = *(const frag8*)(an + (1 * 22 + koff) * 8);
                frag8 na2 = *(const frag8*)(an + (2 * 22 + koff) * 8);
                frag8 na3 = *(const frag8*)(an + (3 * 22 + koff) * 8);
                frag8 nb0 = bn[0], nb1 = bn[64], nb2 = bn[128], nb3 = bn[192];
                // ---- 16 MFMAs on current tap (hide the loads above)
                acc[0][0] = __builtin_amdgcn_mfma_f32_16x16x32_bf16(ca0, cb0, acc[0][0], 0, 0, 0);
                acc[0][1] = __builtin_amdgcn_mfma_f32_16x16x32_bf16(ca0, cb1, acc[0][1], 0, 0, 0);
                acc[0][2] = __builtin_amdgcn_mfma_f32_16x16x32_bf16(ca0, cb2, acc[0][2], 0, 0, 0);
                acc[0][3] = __builtin_amdgcn_mfma_f32_16x16x32_bf16(ca0, cb3, acc[0][3], 0, 0, 0);
                acc[1][0] = __builtin_amdgcn_mfma_f32_16x16x32_bf16(ca1, cb0, acc[1][0], 0, 0, 0);
                acc[1][1] = __builtin_amdgcn_mfma_f32_16x16x32_bf16(ca1, cb1, acc[1][1], 0, 0, 0);
                acc[1][2] = __builtin_amdgcn_mfma_f32_16x16x32_bf16(ca1, cb2, acc[1][2], 0, 0, 0);
                acc[1][3] = __builtin_amdgcn_mfma_f32_16x16x32_bf16(ca1, cb3, acc[1][3], 0, 0, 0);
                acc[2][0] = __builtin_amdgcn_mfma_f32_16x16x32_bf16(ca2, cb0, acc[2][0], 0, 0, 0);
                acc[2][1] = __builtin_amdgcn_mfma_f32_16x16x32_bf16(ca2, cb1, acc[2][1], 0, 0, 0);
                acc[2][2] = __builtin_amdgcn_mfma_f32_16x16x32_bf16(ca2, cb2, acc[2][2], 0, 0, 0);
                acc[2][3] = __builtin_amdgcn_mfma_f32_16x16x32_bf16(ca2, cb3, acc[2][3], 0, 0, 0);
                acc[3][0] = __builtin_amdgcn_mfma_f32_16x16x32_bf16(ca3, cb0, acc[3][0], 0, 0, 0);
                acc[3][1] = __builtin_amdgcn_mfma_f32_16x16x32_bf16(ca3, cb1, acc[3][1], 0, 0, 0);
                acc[3][2] = __builtin_amdgcn_mfma_f32_16x16x32_bf16(ca3, cb2, acc[3][2], 0, 0, 0);
                acc[3][3] = __builtin_amdgcn_mfma_f32_16x16x32_bf16(ca3, cb3, acc[3][3], 0, 0, 0);
                // rotate (unrolled -> pure register renaming)
                ca0 = na0; ca1 = na1; ca2 = na2; ca3 = na3;
                cb0 = nb0; cb1 = nb1; cb2 = nb2; cb3 = nb3;
            }
            arow += 22 * 8;     // next kh row of the A tile
            brow += 7 * 512;    // next row of 7 taps in wz_frag
        }
    }

    // ---- epilogue: D layout col(oc-part)=lane&15, row(px col)=q*4+reg
    //      + fused BN partial sums (per oc: reduce over q-lanes, atomicAdd)
    int prow = h0 + wave * 4;
#pragma unroll
    for (int og = 0; og < 4; og++) {
        int oc = og * 16 + m;
        float bb = bias[oc];
        float s1 = 0.f, s2 = 0.f;
#pragma unroll
        for (int pg = 0; pg < 4; pg++) {
            float* dp = dst + ((size_t)s * KC + oc) * HW
                            + (size_t)(prow + pg) * IMG + w0 + q * 4;
            float4 v;
            v.x = acc[pg][og][0] + bb;
            v.y = acc[pg][og][1] + bb;
            v.z = acc[pg][og][2] + bb;
            v.w = acc[pg][og][3] + bb;
            s1 += v.x + v.y + v.z + v.w;
            s2 += v.x * v.x + v.y * v.y + v.z * v.z + v.w * v.w;
            *(float4*)dp = v;
        }
        // reduce over the 4 q-lanes sharing this oc (lane bits 4,5)
        s1 += __shfl_xor(s1, 16, 64); s2 += __shfl_xor(s2, 16, 64);
        s1 += __shfl_xor(s1, 32, 64); s2 += __shfl_xor(s2, 32, 64);
        if (q == 0) {
            atomicAdd(&pstats[(s * KC + oc) * 2],     s1);
            atomicAdd(&pstats[(s * KC + oc) * 2 + 1], s2);
        }
    }
}

// ---------------------------------------------------------------------------
// Finalize BN stats from fused partial sums; re-zero pstats for next iter.
// ---------------------------------------------------------------------------
__global__ __launch_bounds__(64) void bn_finalize(
        float* __restrict__ pstats,   // [31*64][2] partial sums
        float* __restrict__ stats)    // [31*64][2] -> (mu, rsqrt(var+eps))
{
    int i = blockIdx.x * 64 + threadIdx.x;
    if (i < S31 * KC) {
        float s1 = pstats[i * 2], s2 = pstats[i * 2 + 1];
        pstats[i * 2] = 0.f;
        pstats[i * 2 + 1] = 0.f;
        float mu  = s1 * (1.f / HW);
        float var = s2 * (1.f / HW) - mu * mu;
        if (var < 0.f) var = 0.f;
        stats[i * 2]     = mu;
        stats[i * 2 + 1] = rsqrtf(var + BNEPS);
    }
}

// ---------------------------------------------------------------------------
// Directional gated band scan: each thread owns one (c,h,w), walks 31 bands.
// ---------------------------------------------------------------------------
__global__ __launch_bounds__(256) void band_scan(
        const float* __restrict__ tmp,   // [31,64,HW]
        const float* __restrict__ zpre,  // [31,64,HW]
        const float* __restrict__ stats, // [31*64][2]
        const float* __restrict__ gamma, // [64]
        const float* __restrict__ beta,  // [64]
        float* __restrict__ csc,         // [31,64,HW]
        int fwd)
{
    int idx = blockIdx.x * 256 + threadIdx.x;  // 0 .. 64*HW-1
    int c = idx >> 14;
    float g = gamma[c], be = beta[c];
    float prev = 0.f;
    for (int step = 0; step < S31; step++) {
        int s = fwd ? step : (S31 - 1 - step);
        size_t off = (size_t)s * KC * HW + idx;
        float t  = tmp[off];
        float zp = zpre[off];
        float mu = stats[(s * KC + c) * 2];
        float rs = stats[(s * KC + c) * 2 + 1];
        float zn = (zp - mu) * rs * g + be;
        float z  = 1.f / (1.f + expf(-zn));
        float cur = (step == 0) ? t : (z * prev + (1.f - z) * t);
        csc[off] = cur;
        prev = cur;
    }
}

// ---------------------------------------------------------------------------
extern "C" void kernel_launch(void* const* d_in, const int* in_sizes, int n_in,
                              void* d_out, int out_size, void* d_ws, size_t ws_size,
                              hipStream_t stream) {
    const float* x      = (const float*)d_in[0];   // [1,31,128,128]
    const float* W_fe   = (const float*)d_in[1];
    const float* b_fe   = (const float*)d_in[2];
    const float* W_enc  = (const float*)d_in[3];
    const float* b_enc  = (const float*)d_in[4];
    const float* W_dec  = (const float*)d_in[5];
    const float* b_dec  = (const float*)d_in[6];
    const float* W_last = (const float*)d_in[7];
    const float* b_last = (const float*)d_in[8];
    const float* W_z    = (const float*)d_in[9];
    const float* b_z    = (const float*)d_in[10];
    const float* bn_g   = (const float*)d_in[11];
    const float* bn_b   = (const float*)d_in[12];

    float* out     = (float*)d_out;
    float* csc     = out;                               // [31,1,64,128,128]
    float* outputs = out + (size_t)S31 * KC * HW;       // [1,31,128,128]

    char* ws = (char*)d_ws;
    float* tmp     = (float*)ws; ws += (size_t)S31 * KC * HW * 4;
    float* zpre    = (float*)ws; ws += (size_t)S31 * KC * HW * 4;
    float* res     = (float*)ws; ws += (size_t)S31 * HW * 4;
    float* stats   = (float*)ws; ws += (size_t)S31 * KC * 2 * 4;
    float* pstats  = (float*)ws; ws += (size_t)S31 * KC * 2 * 4;
    short* wz_frag = (short*)ws; ws += ((size_t)3 * KK * 4096 + 4096) * 2; // +1 tap slack (prefetch)
    float* wenc_r  = (float*)ws; ws += (size_t)3 * KK * KC * 4;
    float* wfe_r   = (float*)ws; ws += (size_t)KK * KC * 4;
    short* tmp_t   = (short*)ws; ws += (size_t)2 * S31 * HW * 32 * 2;  // bf16 [pass][s][pix][32]

    // 1) weight reorder / frag-swizzle (+ zero pstats)
    {
        int total = 3 * KK * 4096 + 3 * KK * KC + KK * KC + 2 * S31 * KC;
        reorder_weights<<<(total + 255) / 256, 256, 0, stream>>>(
            W_z, W_enc, W_fe, wz_frag, wenc_r, wfe_r, pstats);
    }

    dim3 gconv(64, S31);     // conv64to1 / conv_z grids
    dim3 gconv2(128, S31);   // conv1to64: 64 tiles x 2 oc-halves

    // 2) csc = softshrink(conv_fe(x))
    conv1to64<<<gconv2, 256, 0, stream>>>(x, wfe_r, b_fe, nullptr, csc, nullptr);

    for (int it = 0; it < 3; it++) {
        int lyr = it;
        // res = x - (conv_dec(csc) + b_dec)
        conv64to1<<<gconv, 256, 0, stream>>>(
            csc, W_dec + (size_t)lyr * KC * KK, b_dec + lyr, x, res);
        // tmp = softshrink(csc + conv_enc(res) + b_enc)  (+ bf16 split copies)
        conv1to64<<<gconv2, 256, 0, stream>>>(
            res, wenc_r + (size_t)lyr * KK * KC, b_enc + (size_t)lyr * KC, csc,
            tmp, tmp_t);
        // zpre = conv_z(tmp) + b_z   (bf16 MFMA shift-GEMM, 4 waves, 1-deep
        //                             A+B software pipeline, split srcT, fused BN)
        conv_z_mfma<<<gconv, 256, 0, stream>>>(
            tmp_t, wz_frag + (size_t)lyr * KK * 4096, b_z + (size_t)lyr * KC,
            zpre, pstats);
        // BN finalize (also re-zeroes pstats for the next iteration)
        bn_finalize<<<S31, 64, 0, stream>>>(pstats, stats);
        // gated directional scan -> csc
        band_scan<<<(KC * HW) / 256, 256, 0, stream>>>(
            tmp, zpre, stats, bn_g + (size_t)lyr * KC, bn_b + (size_t)lyr * KC,
            csc, (it % 2 == 0) ? 1 : 0);
    }

    // 3) outputs = conv_last(csc) + b_last
    conv64to1<<<gconv, 256, 0, stream>>>(csc, W_last, b_last, nullptr, outputs);
}

// Round 10
// 1728.655 us; speedup vs baseline: 1.1877x; 1.0118x over previous
//
#include <hip/hip_runtime.h>
#include <hip/hip_bf16.h>
#include <math.h>

// Problem constants
#define S31   31
#define KC    64
#define KS    7
#define KK    49          // 7*7
#define IMG   128
#define HW    16384       // 128*128
#define LAM   0.1f
#define BNEPS 1e-5f

// conv_z A-tile: plane-major LDS. 4 planes (16B ic-chunks) x 484 pixels,
// HALF the ic range at a time (ks-split, two passes). 30,976 B.
#define PLSTRIDE 3872     // shorts per plane (484 * 8)

// 32x8 tiles for the direct convs (full 128-B cacheline rows)
#define TW    32
#define TH    8
#define DTW   38          // TW + 6
#define DTH   14          // TH + 6
#define DTILE 532         // DTW * DTH

typedef __attribute__((ext_vector_type(8))) short  frag8;   // 8 bf16 (4 VGPRs)
typedef __attribute__((ext_vector_type(4))) float  facc4;   // 4 fp32 acc

// fp32 -> bf16 bits, RNE
static __device__ __forceinline__ short f2bf(float f) {
    union { float f; unsigned u; } x; x.f = f;
    unsigned r = x.u + 0x7fffu + ((x.u >> 16) & 1u);
    return (short)(r >> 16);
}

// ---------------------------------------------------------------------------
// Weight reorder:
//  wz_frag[lyr][khkw][frag f=ks*4+og][lane][j] (bf16) — exact MFMA B-fragment
//    order for 16x16x32: k(=ic) = ks*32 + (lane>>4)*8 + j, n(=oc) = og*16 + (lane&15)
//  wenc_r[lyr][k][oc], wfe_r[k][oc] (fp32)
//  tail: zero pstats (BN partial-sum accumulator)
// ---------------------------------------------------------------------------
__global__ void reorder_weights(const float* __restrict__ Wz,
                                const float* __restrict__ Wenc,
                                const float* __restrict__ Wfe,
                                short* __restrict__ wz_frag,
                                float* __restrict__ wenc_r,
                                float* __restrict__ wfe_r,
                                float* __restrict__ pstats) {
    int tid = blockIdx.x * 256 + threadIdx.x;
    const int NZ = 3 * KK * 4096;         // 602112 frag elements
    const int NE = 3 * KK * KC;           // 9408
    const int NF = KK * KC;               // 3136
    const int NP = 2 * S31 * KC;          // 3968 pstats floats
    if (tid < NZ) {
        int j    = tid & 7;
        int lane = (tid >> 3) & 63;
        int og   = (tid >> 9) & 3;
        int ks   = (tid >> 11) & 1;
        int rem  = tid >> 12;            // lyr*49 + khkw
        int khkw = rem % KK;
        int lyr  = rem / KK;
        int ic = ks * 32 + ((lane >> 4) << 3) + j;
        int oc = (og << 4) + (lane & 15);
        float w = Wz[(((size_t)lyr * KC + oc) * KC + ic) * KK + khkw];
        wz_frag[tid] = f2bf(w);
    } else if (tid < NZ + NE) {
        int t = tid - NZ;
        int oc = t & 63;
        int kk = t >> 6;
        int k  = kk % KK;
        int lyr = kk / KK;
        wenc_r[t] = Wenc[((size_t)lyr * KC + oc) * KK + k];
    } else if (tid < NZ + NE + NF) {
        int t = tid - NZ - NE;
        int oc = t & 63;
        int k  = t >> 6;
        wfe_r[t] = Wfe[oc * KK + k];
    } else if (tid < NZ + NE + NF + NP) {
        pstats[tid - NZ - NE - NF] = 0.f;
    }
}

// ---------------------------------------------------------------------------
// 1 -> 64 channel conv (+optional add) + softshrink.
// 256 threads/block, oc-half on BLOCKIDX (uniform weight addrs -> s_load).
// bf16 copy goes to SPLIT half-buffers dst_t[half][s][pix][32] so that
// conv_z's two ks-passes each read contiguous 64-B granules.
// ---------------------------------------------------------------------------
__global__ __launch_bounds__(256) void conv1to64(
        const float* __restrict__ src,    // [31, HW]
        const float* __restrict__ wr,     // [49*64] layout [k][oc]
        const float* __restrict__ bias,   // [64]
        const float* __restrict__ addsrc, // [31,64,HW] or nullptr
        float* __restrict__ dst,          // [31,64,HW]
        short* __restrict__ dst_t)        // [2][31][HW][32] bf16 or nullptr
{
    int s    = blockIdx.y;
    int half = blockIdx.x & 1;            // 0/1 -> oc 0..31 / 32..63 (UNIFORM)
    int tile = blockIdx.x >> 1;           // 4 tiles in w (32 wide), 16 in h (8 tall)
    int t    = threadIdx.x;
    int tx = t & 31, ty = t >> 5;
    int w0 = (tile & 3) << 5, h0 = (tile >> 2) << 3;

    __shared__ float t_s[DTILE];
    const float* sp = src + (size_t)s * HW;
    for (int i = threadIdx.x; i < DTILE; i += 256) {
        int r = i / DTW, c = i - r * DTW;
        int hh = h0 - 3 + r, ww = w0 - 3 + c;
        t_s[i] = (hh >= 0 && hh < IMG && ww >= 0 && ww < IMG) ? sp[hh * IMG + ww] : 0.f;
    }
    __syncthreads();

    int pix = (h0 + ty) * IMG + (w0 + tx);
    size_t base = ((size_t)s * KC + half * 32) * HW + pix;

    // 32-deep prefetch of addsrc (issued before the compute loop, kept live)
    float addv[32];
    if (addsrc) {
#pragma unroll
        for (int i = 0; i < 32; i++) addv[i] = addsrc[base + (size_t)i * HW];
    } else {
#pragma unroll
        for (int i = 0; i < 32; i++) addv[i] = 0.f;
    }
    __builtin_amdgcn_sched_barrier(0);   // keep the loads issued up here

    float acc[32];
#pragma unroll
    for (int i = 0; i < 32; i++) acc[i] = 0.f;

    const float* wrh = wr + half * 32;   // uniform -> scalar loads below
#pragma unroll 1
    for (int kh = 0; kh < KS; kh++) {
#pragma unroll
        for (int kw = 0; kw < KS; kw++) {
            float v = t_s[(ty + kh) * DTW + tx + kw];
            const float* wk = wrh + (kh * KS + kw) * KC;
#pragma unroll
            for (int i = 0; i < 32; i++) acc[i] += v * wk[i];
        }
    }

    short* tb = dst_t ? (dst_t + (((size_t)half * S31 + s) * HW + pix) * 32) : nullptr;
#pragma unroll
    for (int g = 0; g < 4; g++) {
        frag8 vv;
#pragma unroll
        for (int j = 0; j < 8; j++) {
            int i = g * 8 + j;
            float v = acc[i] + bias[half * 32 + i];   // same assoc order as R7
            v += addv[i];                             // (+0.0f when no addsrc)
            v = (v > LAM) ? (v - LAM) : ((v < -LAM) ? (v + LAM) : 0.f);
            dst[base + (size_t)i * HW] = v;
            vv[j] = f2bf(v);
        }
        if (tb) *(frag8*)(tb + g * 8) = vv;
    }
}

// ---------------------------------------------------------------------------
// 64 -> 1 channel conv. If xsub != null, out = xsub - (conv+b); else conv+b.
// 32x8 tile; ic staged 4 planes/round, double-buffered LDS with register
// prefetch. Accumulation order (ic asc, kh, kw) identical -> bit-exact.
// ---------------------------------------------------------------------------
#define ICB   4
#define CHUNK (ICB * DTILE)   // 2128

__global__ __launch_bounds__(256) void conv64to1(
        const float* __restrict__ src,   // [31,64,HW]
        const float* __restrict__ w,     // [64*49] layout [ic][k]
        const float* __restrict__ bias,  // [1]
        const float* __restrict__ xsub,  // [31,HW] or nullptr
        float* __restrict__ dst)         // [31,HW]
{
    int s    = blockIdx.y;
    int tile = blockIdx.x;
    int tx = threadIdx.x & 31, ty = threadIdx.x >> 5;
    int w0 = (tile & 3) << 5, h0 = (tile >> 2) << 3;

    __shared__ float t_s[2][CHUNK];      // 17 KB

    // per-thread load slots: identical pattern every chunk, precompute once
    int  goff[9];
    bool okf[9];
#pragma unroll
    for (int r = 0; r < 9; r++) {
        int j = threadIdx.x + r * 256;
        if (j < CHUNK) {
            int plane = j / DTILE, p = j - plane * DTILE;
            int rr = p / DTW, cc = p - rr * DTW;
            int hh = h0 - 3 + rr, ww = w0 - 3 + cc;
            bool inb = (hh >= 0 && hh < IMG && ww >= 0 && ww < IMG);
            goff[r] = plane * HW + (inb ? (hh * IMG + ww) : 0);
            okf[r]  = inb;
        }
    }

    const float* sbase = src + (size_t)s * KC * HW;

    // stage chunk 0
    float ldv[9];
#pragma unroll
    for (int r = 0; r < 9; r++)
        if (threadIdx.x + r * 256 < CHUNK)
            ldv[r] = okf[r] ? sbase[goff[r]] : 0.f;
#pragma unroll
    for (int r = 0; r < 9; r++)
        if (threadIdx.x + r * 256 < CHUNK)
            t_s[0][threadIdx.x + r * 256] = ldv[r];

    float acc = 0.f;
    __syncthreads();

#pragma unroll 1
    for (int blk = 0; blk < 16; blk++) {
        int cur = blk & 1;
        // prefetch next chunk into regs (overlaps the compute below)
        if (blk < 15) {
            const float* nb = sbase + (size_t)(blk + 1) * ICB * HW;
#pragma unroll
            for (int r = 0; r < 9; r++)
                if (threadIdx.x + r * 256 < CHUNK)
                    ldv[r] = okf[r] ? nb[goff[r]] : 0.f;
        }
        __builtin_amdgcn_sched_barrier(0);
        // compute 4 planes of this chunk
#pragma unroll
        for (int pl = 0; pl < ICB; pl++) {
            int ic = blk * ICB + pl;
            const float* wk = w + ic * KK;
            const float* ts = &t_s[cur][pl * DTILE];
#pragma unroll 1
            for (int kh = 0; kh < KS; kh++) {
#pragma unroll
                for (int kw = 0; kw < KS; kw++)
                    acc += ts[(ty + kh) * DTW + tx + kw] * wk[kh * KS + kw];
            }
        }
        __syncthreads();
        if (blk < 15) {
#pragma unroll
            for (int r = 0; r < 9; r++)
                if (threadIdx.x + r * 256 < CHUNK)
                    t_s[cur ^ 1][threadIdx.x + r * 256] = ldv[r];
            __syncthreads();
        }
    }

    float v = acc + bias[0];
    int pix = (h0 + ty) * IMG + (w0 + tx);
    if (xsub) v = xsub[(size_t)s * HW + pix] - v;
    dst[(size_t)s * HW + pix] = v;
}

// ---------------------------------------------------------------------------
// conv_z as bf16 MFMA shift-GEMM.
// R10: ROLLING A-WINDOW + 2-DEEP B PREFETCH.
//   Counter archaeology: SQ_LDS_BANK_CONFLICT has been ~3.9 cyc per compute
//   ds_read in EVERY round (R9: 1.244e7/3.17e6; R4 straight-line CSE'd the
//   overlapping rows -> 0.357x reads AND 0.357x conflicts). So: read less.
//   Loop nest swapped to kw-outer / kh-inner(unrolled). Taps (kh,kw) and
//   (kh+1,kw) share 3 of 4 A rows -> rolling 4-row register window: per kw,
//   4 preload reads + 1 new row per kh = 70 reads/pass-wave (was 196+4).
//   B prefetched 2 TAPS ahead (p-regs for kh+2): 2x~128cyc MFMA cover >= L2
//   latency (B streams 196 KB/pass through 32 KB L1 -> mostly L2 hits).
//   Regs: 64 acc AGPR + A 20 + B 48 + addr ~ 150 <= 168 @ (256,3).
// srcT SPLIT per pass [pass][s][pix][32]; ks-split LDS 30,976 B.
// Accumulation per acc element still sums all 49 taps (kw-major order now —
// ULP-level fp shift only, same class as R6's pass reorder).
// ---------------------------------------------------------------------------
__global__ __launch_bounds__(256, 3) void conv_z_mfma(
        const short* __restrict__ srcT,  // [2][31][HW][32] bf16 (tmp_t halves)
        const short* __restrict__ wfrag, // per-layer B-frag buffer (bf16 bits)
        const float* __restrict__ bias,  // [64]
        float* __restrict__ dst,         // [31,64,HW] (zpre)
        float* __restrict__ pstats)      // [31*64][2] partial sums (pre-zeroed)
{
    __shared__ __align__(16) short a_s[4 * PLSTRIDE]; // 30,976 B

    int s    = blockIdx.y;
    int tile = blockIdx.x;
    int h0 = (tile >> 3) << 4, w0 = (tile & 7) << 4;
    int tid  = threadIdx.x;
    int wave = tid >> 6, lane = tid & 63;
    int q = lane >> 4, m = lane & 15;

    facc4 acc[4][4];
#pragma unroll
    for (int i = 0; i < 4; i++)
#pragma unroll
        for (int j = 0; j < 4; j++)
            acc[i][j] = (facc4){0.f, 0.f, 0.f, 0.f};

#pragma unroll 1
    for (int pass = 0; pass < 2; ++pass) {
        if (pass) __syncthreads();       // all pass-0 reads done before overwrite

        // ---- stage ic half [pass*32, pass*32+32) -> planes 0..3 (b128 only)
        const short* tsrc = srcT + ((size_t)pass * S31 + s) * HW * 32;
#pragma unroll
        for (int rep = 0; rep < 2; rep++) {
            int p = tid + rep * 256;
            if (p < 484) {
                int r = p / 22, c = p - r * 22;
                int hh = h0 - 3 + r, ww = w0 - 3 + c;
                bool ok = (hh >= 0 && hh < IMG && ww >= 0 && ww < IMG);
                const short* px = tsrc + (size_t)(ok ? (hh * IMG + ww) : 0) * 32;
                short* dp = a_s + p * 8;
#pragma unroll
                for (int c4 = 0; c4 < 4; c4++) {
                    frag8 v;
                    if (ok) v = *(const frag8*)(px + (c4 << 3));
                    else    v = (frag8)(short)0;
                    *(frag8*)(dp + c4 * PLSTRIDE) = v;
                }
            }
        }
        __syncthreads();

        const frag8* bbase = (const frag8*)wfrag + (pass * 4) * 64 + lane;

#pragma unroll 1
        for (int kw = 0; kw < 7; ++kw) {
            // per-lane A column base for this kw: rows counted from wave*4
            const short* acol = a_s + q * PLSTRIDE + (wave * 4 * 22 + m + kw) * 8;
            const frag8* bk = bbase + kw * 512;   // tap (kh=0, kw)

            // preload A rows 0..3 (window) and B for kh=0 (cur) + kh=1 (next)
            frag8 a0 = *(const frag8*)(acol + 0 * 176);
            frag8 a1 = *(const frag8*)(acol + 1 * 176);
            frag8 a2 = *(const frag8*)(acol + 2 * 176);
            frag8 a3 = *(const frag8*)(acol + 3 * 176);
            frag8 c0 = bk[0], c1 = bk[64], c2 = bk[128], c3 = bk[192];
            const frag8* bk1 = bk + 7 * 512;
            frag8 n0 = bk1[0], n1 = bk1[64], n2 = bk1[128], n3 = bk1[192];

#pragma unroll
            for (int kh = 0; kh < 7; ++kh) {
                // ---- issue: B for tap (kh+2, kw)  [2-deep pipeline]
                frag8 p0, p1, p2, p3;
                if (kh < 5) {
                    const frag8* bk2 = bk + (kh + 2) * (7 * 512);
                    p0 = bk2[0]; p1 = bk2[64]; p2 = bk2[128]; p3 = bk2[192];
                }
                // ---- issue: next A row (row kh+4 of window; max 9 -> row 21)
                frag8 an;
                if (kh < 6) an = *(const frag8*)(acol + (kh + 4) * 176);
                // ---- 16 MFMAs on tap (kh, kw): a_pg = row wave*4+kh+pg
                acc[0][0] = __builtin_amdgcn_mfma_f32_16x16x32_bf16(a0, c0, acc[0][0], 0, 0, 0);
                acc[0][1] = __builtin_amdgcn_mfma_f32_16x16x32_bf16(a0, c1, acc[0][1], 0, 0, 0);
                acc[0][2] = __builtin_amdgcn_mfma_f32_16x16x32_bf16(a0, c2, acc[0][2], 0, 0, 0);
                acc[0][3] = __builtin_amdgcn_mfma_f32_16x16x32_bf16(a0, c3, acc[0][3], 0, 0, 0);
                acc[1][0] = __builtin_amdgcn_mfma_f32_16x16x32_bf16(a1, c0, acc[1][0], 0, 0, 0);
                acc[1][1] = __builtin_amdgcn_mfma_f32_16x16x32_bf16(a1, c1, acc[1][1], 0, 0, 0);
                acc[1][2] = __builtin_amdgcn_mfma_f32_16x16x32_bf16(a1, c2, acc[1][2], 0, 0, 0);
                acc[1][3] = __builtin_amdgcn_mfma_f32_16x16x32_bf16(a1, c3, acc[1][3], 0, 0, 0);
                acc[2][0] = __builtin_amdgcn_mfma_f32_16x16x32_bf16(a2, c0, acc[2][0], 0, 0, 0);
                acc[2][1] = __builtin_amdgcn_mfma_f32_16x16x32_bf16(a2, c1, acc[2][1], 0, 0, 0);
                acc[2][2] = __builtin_amdgcn_mfma_f32_16x16x32_bf16(a2, c2, acc[2][2], 0, 0, 0);
                acc[2][3] = __builtin_amdgcn_mfma_f32_16x16x32_bf16(a2, c3, acc[2][3], 0, 0, 0);
                acc[3][0] = __builtin_amdgcn_mfma_f32_16x16x32_bf16(a3, c0, acc[3][0], 0, 0, 0);
                acc[3][1] = __builtin_amdgcn_mfma_f32_16x16x32_bf16(a3, c1, acc[3][1], 0, 0, 0);
                acc[3][2] = __builtin_amdgcn_mfma_f32_16x16x32_bf16(a3, c2, acc[3][2], 0, 0, 0);
                acc[3][3] = __builtin_amdgcn_mfma_f32_16x16x32_bf16(a3, c3, acc[3][3], 0, 0, 0);
                // ---- rotate windows (unrolled -> pure register renaming)
                a0 = a1; a1 = a2; a2 = a3;
                if (kh < 6) a3 = an;
                c0 = n0; c1 = n1; c2 = n2; c3 = n3;
                if (kh < 5) { n0 = p0; n1 = p1; n2 = p2; n3 = p3; }
            }
        }
    }

    // ---- epilogue: D layout col(oc-part)=lane&15, row(px col)=q*4+reg
    //      + fused BN partial sums (per oc: reduce over q-lanes, atomicAdd)
    int prow = h0 + wave * 4;
#pragma unroll
    for (int og = 0; og < 4; og++) {
        int oc = og * 16 + m;
        float bb = bias[oc];
        float s1 = 0.f, s2 = 0.f;
#pragma unroll
        for (int pg = 0; pg < 4; pg++) {
            float* dp = dst + ((size_t)s * KC + oc) * HW
                            + (size_t)(prow + pg) * IMG + w0 + q * 4;
            float4 v;
            v.x = acc[pg][og][0] + bb;
            v.y = acc[pg][og][1] + bb;
            v.z = acc[pg][og][2] + bb;
            v.w = acc[pg][og][3] + bb;
            s1 += v.x + v.y + v.z + v.w;
            s2 += v.x * v.x + v.y * v.y + v.z * v.z + v.w * v.w;
            *(float4*)dp = v;
        }
        // reduce over the 4 q-lanes sharing this oc (lane bits 4,5)
        s1 += __shfl_xor(s1, 16, 64); s2 += __shfl_xor(s2, 16, 64);
        s1 += __shfl_xor(s1, 32, 64); s2 += __shfl_xor(s2, 32, 64);
        if (q == 0) {
            atomicAdd(&pstats[(s * KC + oc) * 2],     s1);
            atomicAdd(&pstats[(s * KC + oc) * 2 + 1], s2);
        }
    }
}

// ---------------------------------------------------------------------------
// Finalize BN stats from fused partial sums; re-zero pstats for next iter.
// ---------------------------------------------------------------------------
__global__ __launch_bounds__(64) void bn_finalize(
        float* __restrict__ pstats,   // [31*64][2] partial sums
        float* __restrict__ stats)    // [31*64][2] -> (mu, rsqrt(var+eps))
{
    int i = blockIdx.x * 64 + threadIdx.x;
    if (i < S31 * KC) {
        float s1 = pstats[i * 2], s2 = pstats[i * 2 + 1];
        pstats[i * 2] = 0.f;
        pstats[i * 2 + 1] = 0.f;
        float mu  = s1 * (1.f / HW);
        float var = s2 * (1.f / HW) - mu * mu;
        if (var < 0.f) var = 0.f;
        stats[i * 2]     = mu;
        stats[i * 2 + 1] = rsqrtf(var + BNEPS);
    }
}

// ---------------------------------------------------------------------------
// Directional gated band scan: each thread owns one (c,h,w), walks 31 bands.
// ---------------------------------------------------------------------------
__global__ __launch_bounds__(256) void band_scan(
        const float* __restrict__ tmp,   // [31,64,HW]
        const float* __restrict__ zpre,  // [31,64,HW]
        const float* __restrict__ stats, // [31*64][2]
        const float* __restrict__ gamma, // [64]
        const float* __restrict__ beta,  // [64]
        float* __restrict__ csc,         // [31,64,HW]
        int fwd)
{
    int idx = blockIdx.x * 256 + threadIdx.x;  // 0 .. 64*HW-1
    int c = idx >> 14;
    float g = gamma[c], be = beta[c];
    float prev = 0.f;
    for (int step = 0; step < S31; step++) {
        int s = fwd ? step : (S31 - 1 - step);
        size_t off = (size_t)s * KC * HW + idx;
        float t  = tmp[off];
        float zp = zpre[off];
        float mu = stats[(s * KC + c) * 2];
        float rs = stats[(s * KC + c) * 2 + 1];
        float zn = (zp - mu) * rs * g + be;
        float z  = 1.f / (1.f + expf(-zn));
        float cur = (step == 0) ? t : (z * prev + (1.f - z) * t);
        csc[off] = cur;
        prev = cur;
    }
}

// ---------------------------------------------------------------------------
extern "C" void kernel_launch(void* const* d_in, const int* in_sizes, int n_in,
                              void* d_out, int out_size, void* d_ws, size_t ws_size,
                              hipStream_t stream) {
    const float* x      = (const float*)d_in[0];   // [1,31,128,128]
    const float* W_fe   = (const float*)d_in[1];
    const float* b_fe   = (const float*)d_in[2];
    const float* W_enc  = (const float*)d_in[3];
    const float* b_enc  = (const float*)d_in[4];
    const float* W_dec  = (const float*)d_in[5];
    const float* b_dec  = (const float*)d_in[6];
    const float* W_last = (const float*)d_in[7];
    const float* b_last = (const float*)d_in[8];
    const float* W_z    = (const float*)d_in[9];
    const float* b_z    = (const float*)d_in[10];
    const float* bn_g   = (const float*)d_in[11];
    const float* bn_b   = (const float*)d_in[12];

    float* out     = (float*)d_out;
    float* csc     = out;                               // [31,1,64,128,128]
    float* outputs = out + (size_t)S31 * KC * HW;       // [1,31,128,128]

    char* ws = (char*)d_ws;
    float* tmp     = (float*)ws; ws += (size_t)S31 * KC * HW * 4;
    float* zpre    = (float*)ws; ws += (size_t)S31 * KC * HW * 4;
    float* res     = (float*)ws; ws += (size_t)S31 * HW * 4;
    float* stats   = (float*)ws; ws += (size_t)S31 * KC * 2 * 4;
    float* pstats  = (float*)ws; ws += (size_t)S31 * KC * 2 * 4;
    short* wz_frag = (short*)ws; ws += ((size_t)3 * KK * 4096 + 4096) * 2; // +1 tap slack
    float* wenc_r  = (float*)ws; ws += (size_t)3 * KK * KC * 4;
    float* wfe_r   = (float*)ws; ws += (size_t)KK * KC * 4;
    short* tmp_t   = (short*)ws; ws += (size_t)2 * S31 * HW * 32 * 2;  // bf16 [pass][s][pix][32]

    // 1) weight reorder / frag-swizzle (+ zero pstats)
    {
        int total = 3 * KK * 4096 + 3 * KK * KC + KK * KC + 2 * S31 * KC;
        reorder_weights<<<(total + 255) / 256, 256, 0, stream>>>(
            W_z, W_enc, W_fe, wz_frag, wenc_r, wfe_r, pstats);
    }

    dim3 gconv(64, S31);     // conv64to1 / conv_z grids
    dim3 gconv2(128, S31);   // conv1to64: 64 tiles x 2 oc-halves

    // 2) csc = softshrink(conv_fe(x))
    conv1to64<<<gconv2, 256, 0, stream>>>(x, wfe_r, b_fe, nullptr, csc, nullptr);

    for (int it = 0; it < 3; it++) {
        int lyr = it;
        // res = x - (conv_dec(csc) + b_dec)
        conv64to1<<<gconv, 256, 0, stream>>>(
            csc, W_dec + (size_t)lyr * KC * KK, b_dec + lyr, x, res);
        // tmp = softshrink(csc + conv_enc(res) + b_enc)  (+ bf16 split copies)
        conv1to64<<<gconv2, 256, 0, stream>>>(
            res, wenc_r + (size_t)lyr * KK * KC, b_enc + (size_t)lyr * KC, csc,
            tmp, tmp_t);
        // zpre = conv_z(tmp) + b_z   (bf16 MFMA shift-GEMM, rolling A-window,
        //                             2-deep B prefetch, split srcT, fused BN)
        conv_z_mfma<<<gconv, 256, 0, stream>>>(
            tmp_t, wz_frag + (size_t)lyr * KK * 4096, b_z + (size_t)lyr * KC,
            zpre, pstats);
        // BN finalize (also re-zeroes pstats for the next iteration)
        bn_finalize<<<S31, 64, 0, stream>>>(pstats, stats);
        // gated directional scan -> csc
        band_scan<<<(KC * HW) / 256, 256, 0, stream>>>(
            tmp, zpre, stats, bn_g + (size_t)lyr * KC, bn_b + (size_t)lyr * KC,
            csc, (it % 2 == 0) ? 1 : 0);
    }

    // 3) outputs = conv_last(csc) + b_last
    conv64to1<<<gconv, 256, 0, stream>>>(csc, W_last, b_last, nullptr, outputs);
}